// Round 1
// baseline (237.098 us; speedup 1.0000x reference)
//
#include <hip/hip_runtime.h>

typedef __attribute__((ext_vector_type(8))) short short8v;
typedef __attribute__((ext_vector_type(4))) float f32x4;

__device__ __forceinline__ ushort f2bf(float f) {
  union { float f; unsigned int u; } c; c.f = f;
  return (ushort)((c.u + 0x7FFFu + ((c.u >> 16) & 1u)) >> 16);
}

// ---- setup: convert weights to bf16, pre-gather rel-pos bias to [3][64][64] f32
__global__ __launch_bounds__(256) void setup_k(
    const float* __restrict__ qkv_w, const float* __restrict__ proj_w,
    const float* __restrict__ bias_table, const int* __restrict__ rel_idx,
    ushort* __restrict__ qkv_wb, ushort* __restrict__ proj_wb,
    float* __restrict__ bias_comb) {
  int idx = blockIdx.x * 256 + threadIdx.x;
  if (idx < 27648) {                       // 288*96
    qkv_wb[idx] = f2bf(qkv_w[idx]);
  } else if (idx < 36864) {                // + 96*96
    int i = idx - 27648;
    proj_wb[i] = f2bf(proj_w[i]);
  } else if (idx < 49152) {                // + 3*64*64
    int i = idx - 36864;
    int h = i / 4096, rc = i % 4096;
    bias_comb[i] = bias_table[rel_idx[rc] * 3 + h];
  }
}

// ---- main fused kernel: one block per window
__global__ __launch_bounds__(256, 2) void winattn(
    const float* __restrict__ x, const float* __restrict__ mask,
    const float* __restrict__ qkv_b, const float* __restrict__ proj_b,
    const ushort* __restrict__ qkv_wb, const ushort* __restrict__ proj_wb,
    const float* __restrict__ bias_comb, float* __restrict__ out) {
  // bank strides: 104*2=208B(13*16), 200*2=400B(25*16), 72*2=144B(9*16) -> all
  // 16B aligned rows, bank stride ≡ 4 mod 32 => worst 2-way (free).
  __shared__ ushort xs[64][104];   // x bf16, later reused for attn-out [64][96]
  __shared__ ushort qks[64][200];  // q (cols 0..95, pre-scaled) | k (96..191)
  __shared__ ushort vts[96][72];   // v transposed: [h*32+d][token]
  __shared__ ushort ps[4][16][72]; // per-wave P tile (bf16, unnormalized)

  const int b = blockIdx.x;
  const int t = threadIdx.x;
  const int w = t >> 6;       // wave id = M-tile
  const int lane = t & 63;
  const int l15 = lane & 15;
  const int g = lane >> 4;    // 16-lane group

  // phase 0: x -> bf16 LDS
  {
    const float* xb = x + (size_t)b * 6144;
    #pragma unroll
    for (int i = 0; i < 6; ++i) {
      int e = i * 1024 + t * 4;
      const float4 v4 = *reinterpret_cast<const float4*>(xb + e);
      int row = e / 96, col = e % 96;              // 96%4==0: no row crossing
      ushort4 pk = make_ushort4(f2bf(v4.x), f2bf(v4.y), f2bf(v4.z), f2bf(v4.w));
      *reinterpret_cast<ushort4*>(&xs[row][col]) = pk;
    }
  }
  __syncthreads();

  // phase 1: QKV GEMM  [64x96]x[96x288], wave w owns rows w*16..w*16+15
  {
    short8v xa[3];
    const int arow = w * 16 + l15;
    #pragma unroll
    for (int ks = 0; ks < 3; ++ks)
      xa[ks] = *reinterpret_cast<const short8v*>(&xs[arow][ks * 32 + g * 8]);

    #pragma unroll
    for (int nt = 0; nt < 18; ++nt) {
      const int cw = nt * 16 + l15;   // output channel (also B-fragment row)
      f32x4 acc = {0.f, 0.f, 0.f, 0.f};
      #pragma unroll
      for (int ks = 0; ks < 3; ++ks) {
        short8v bf = *reinterpret_cast<const short8v*>(qkv_wb + cw * 96 + ks * 32 + g * 8);
        acc = __builtin_amdgcn_mfma_f32_16x16x32_bf16(xa[ks], bf, acc, 0, 0, 0);
      }
      const float bias = qkv_b[cw];
      const int r0 = w * 16 + g * 4;
      if (nt < 12) {                  // q or k -> row-major [token][chan]
        const float qs = (nt < 6) ? 0.17677669529663687f : 1.0f;  // 1/sqrt(32)
        #pragma unroll
        for (int r = 0; r < 4; ++r)
          qks[r0 + r][cw] = f2bf((acc[r] + bias) * qs);
      } else {                        // v -> transposed [chan][token], 8B packed
        ushort4 pk = make_ushort4(f2bf(acc[0] + bias), f2bf(acc[1] + bias),
                                  f2bf(acc[2] + bias), f2bf(acc[3] + bias));
        *reinterpret_cast<ushort4*>(&vts[cw - 192][r0]) = pk;
      }
    }
  }
  __syncthreads();

  // phase 2: per-head attention; wave w owns score rows w*16..w*16+15
  const float* maskw = mask + (size_t)(b & 4095) * 4096;
  for (int h = 0; h < 3; ++h) {
    short8v aq = *reinterpret_cast<const short8v*>(&qks[w * 16 + l15][h * 32 + g * 8]);
    f32x4 s[4];
    #pragma unroll
    for (int tj = 0; tj < 4; ++tj) {
      short8v bk = *reinterpret_cast<const short8v*>(&qks[tj * 16 + l15][96 + h * 32 + g * 8]);
      f32x4 z = {0.f, 0.f, 0.f, 0.f};
      s[tj] = __builtin_amdgcn_mfma_f32_16x16x32_bf16(aq, bk, z, 0, 0, 0);
    }
    // add rel-pos bias + shift mask; fp32 softmax (rows live in 16-lane groups)
    float mx[4] = {-1e30f, -1e30f, -1e30f, -1e30f};
    #pragma unroll
    for (int tj = 0; tj < 4; ++tj) {
      #pragma unroll
      for (int r = 0; r < 4; ++r) {
        const int i = w * 16 + g * 4 + r;
        const int j = tj * 16 + l15;
        float v = s[tj][r] + bias_comb[h * 4096 + i * 64 + j] + maskw[i * 64 + j];
        s[tj][r] = v;
        mx[r] = fmaxf(mx[r], v);
      }
    }
    #pragma unroll
    for (int r = 0; r < 4; ++r) {
      mx[r] = fmaxf(mx[r], __shfl_xor(mx[r], 1));
      mx[r] = fmaxf(mx[r], __shfl_xor(mx[r], 2));
      mx[r] = fmaxf(mx[r], __shfl_xor(mx[r], 4));
      mx[r] = fmaxf(mx[r], __shfl_xor(mx[r], 8));
    }
    float sm[4] = {0.f, 0.f, 0.f, 0.f};
    #pragma unroll
    for (int tj = 0; tj < 4; ++tj) {
      #pragma unroll
      for (int r = 0; r < 4; ++r) {
        float p = __expf(s[tj][r] - mx[r]);
        s[tj][r] = p;
        sm[r] += p;
      }
    }
    #pragma unroll
    for (int r = 0; r < 4; ++r) {
      sm[r] += __shfl_xor(sm[r], 1);
      sm[r] += __shfl_xor(sm[r], 2);
      sm[r] += __shfl_xor(sm[r], 4);
      sm[r] += __shfl_xor(sm[r], 8);
    }
    float inv[4];
    #pragma unroll
    for (int r = 0; r < 4; ++r) inv[r] = 1.0f / sm[r];

    // P (unnormalized, <=1) -> bf16 wave-private LDS in A-fragment layout
    #pragma unroll
    for (int tj = 0; tj < 4; ++tj)
      #pragma unroll
      for (int r = 0; r < 4; ++r)
        ps[w][g * 4 + r][tj * 16 + l15] = f2bf(s[tj][r]);
    __syncthreads();

    // PV: out[16x32] = P[16x64] @ V[64x32]; normalization folded into output
    short8v ap[2];
    #pragma unroll
    for (int ks = 0; ks < 2; ++ks)
      ap[ks] = *reinterpret_cast<const short8v*>(&ps[w][l15][ks * 32 + g * 8]);
    #pragma unroll
    for (int nt = 0; nt < 2; ++nt) {
      f32x4 o = {0.f, 0.f, 0.f, 0.f};
      #pragma unroll
      for (int ks = 0; ks < 2; ++ks) {
        short8v bv = *reinterpret_cast<const short8v*>(&vts[h * 32 + nt * 16 + l15][ks * 32 + g * 8]);
        o = __builtin_amdgcn_mfma_f32_16x16x32_bf16(ap[ks], bv, o, 0, 0, 0);
      }
      #pragma unroll
      for (int r = 0; r < 4; ++r)
        xs[w * 16 + g * 4 + r][h * 32 + nt * 16 + l15] = f2bf(o[r] * inv[r]);
    }
    __syncthreads();
  }

  // phase 3: output projection [64x96]x[96x96] + bias -> f32 out
  {
    short8v oa[3];
    #pragma unroll
    for (int ks = 0; ks < 3; ++ks)
      oa[ks] = *reinterpret_cast<const short8v*>(&xs[w * 16 + l15][ks * 32 + g * 8]);
    float* ob = out + (size_t)b * 6144;
    #pragma unroll
    for (int nt = 0; nt < 6; ++nt) {
      const int ch = nt * 16 + l15;
      f32x4 acc = {0.f, 0.f, 0.f, 0.f};
      #pragma unroll
      for (int ks = 0; ks < 3; ++ks) {
        short8v bf = *reinterpret_cast<const short8v*>(proj_wb + ch * 96 + ks * 32 + g * 8);
        acc = __builtin_amdgcn_mfma_f32_16x16x32_bf16(oa[ks], bf, acc, 0, 0, 0);
      }
      const float pb = proj_b[ch];
      #pragma unroll
      for (int r = 0; r < 4; ++r)
        ob[(w * 16 + g * 4 + r) * 96 + ch] = acc[r] + pb;
    }
  }
}

extern "C" void kernel_launch(void* const* d_in, const int* in_sizes, int n_in,
                              void* d_out, int out_size, void* d_ws, size_t ws_size,
                              hipStream_t stream) {
  const float* x          = (const float*)d_in[0];
  const float* mask       = (const float*)d_in[1];
  const float* qkv_w      = (const float*)d_in[2];
  const float* qkv_b      = (const float*)d_in[3];
  const float* proj_w     = (const float*)d_in[4];
  const float* proj_b     = (const float*)d_in[5];
  const float* bias_table = (const float*)d_in[6];
  const int*   rel_idx    = (const int*)d_in[7];

  char* ws = (char*)d_ws;
  ushort* qkv_wb   = (ushort*)ws;                    // 288*96*2 = 55296 B
  ushort* proj_wb  = (ushort*)(ws + 55296);          // 96*96*2  = 18432 B
  float*  bias_comb = (float*)(ws + 55296 + 18432);  // 3*64*64*4 = 49152 B

  setup_k<<<192, 256, 0, stream>>>(qkv_w, proj_w, bias_table, rel_idx,
                                   qkv_wb, proj_wb, bias_comb);
  winattn<<<8192, 256, 0, stream>>>(x, mask, qkv_b, proj_b,
                                    qkv_wb, proj_wb, bias_comb, (float*)d_out);
}

// Round 2
// 232.476 us; speedup vs baseline: 1.0199x; 1.0199x over previous
//
#include <hip/hip_runtime.h>

typedef __attribute__((ext_vector_type(8))) short short8v;
typedef __attribute__((ext_vector_type(4))) float f32x4;

__device__ __forceinline__ ushort f2bf(float f) {
  union { float f; unsigned int u; } c; c.f = f;
  return (ushort)((c.u + 0x7FFFu + ((c.u >> 16) & 1u)) >> 16);
}

// ---- setup: convert weights to bf16, pre-gather rel-pos bias to [3][64][64] f32
__global__ __launch_bounds__(256) void setup_k(
    const float* __restrict__ qkv_w, const float* __restrict__ proj_w,
    const float* __restrict__ bias_table, const int* __restrict__ rel_idx,
    ushort* __restrict__ qkv_wb, ushort* __restrict__ proj_wb,
    float* __restrict__ bias_comb) {
  int idx = blockIdx.x * 256 + threadIdx.x;
  if (idx < 27648) {                       // 288*96
    qkv_wb[idx] = f2bf(qkv_w[idx]);
  } else if (idx < 36864) {                // + 96*96
    int i = idx - 27648;
    proj_wb[i] = f2bf(proj_w[i]);
  } else if (idx < 49152) {                // + 3*64*64
    int i = idx - 36864;
    int h = i / 4096, rc = i % 4096;
    bias_comb[i] = bias_table[rel_idx[rc] * 3 + h];
  }
}

// ---- main fused kernel: one block per window, 4 waves, ONE barrier.
// LDS = klds 13312 + vts 13824 + ps 13312 = 40448 B -> 4 blocks/CU.
__global__ __launch_bounds__(256, 4) void winattn(
    const float* __restrict__ x, const float* __restrict__ mask,
    const float* __restrict__ qkv_b, const float* __restrict__ proj_b,
    const ushort* __restrict__ qkv_wb, const ushort* __restrict__ proj_wb,
    const float* __restrict__ bias_comb, float* __restrict__ out) {
  // row strides: 104*2=208B (13*16B, odd slot count -> conflict-free b128),
  //              72*2=144B (9*16B).
  __shared__ ushort klds[64][104];  // k row-major [token][chan 0..95]
  __shared__ ushort vts[96][72];    // v transposed [chan][token]
  __shared__ ushort ps[4][16][104]; // wave-private scratch: q(96) / P(64) / O(32)

  const int bb = blockIdx.x;
  const int t = threadIdx.x;
  const int w = t >> 6;       // wave id = 16-row M-tile
  const int lane = t & 63;
  const int l15 = lane & 15;
  const int g = lane >> 4;    // 16-lane group

  // phase A: x A-fragments straight from global (own 16 rows only)
  short8v xa[3];
  {
    const float* xrow = x + ((size_t)bb * 64 + w * 16 + l15) * 96 + g * 8;
    #pragma unroll
    for (int ks3 = 0; ks3 < 3; ++ks3) {
      float4 a0 = *reinterpret_cast<const float4*>(xrow + ks3 * 32);
      float4 a1 = *reinterpret_cast<const float4*>(xrow + ks3 * 32 + 4);
      short8v v;
      v[0] = (short)f2bf(a0.x); v[1] = (short)f2bf(a0.y);
      v[2] = (short)f2bf(a0.z); v[3] = (short)f2bf(a0.w);
      v[4] = (short)f2bf(a1.x); v[5] = (short)f2bf(a1.y);
      v[6] = (short)f2bf(a1.z); v[7] = (short)f2bf(a1.w);
      xa[ks3] = v;
    }
  }

  // phase B: QKV GEMM [16x96]x[96x288] per wave; q -> wave scratch, k/v -> LDS
  #pragma unroll
  for (int nt = 0; nt < 18; ++nt) {
    const int cw = nt * 16 + l15;
    f32x4 acc = {0.f, 0.f, 0.f, 0.f};
    #pragma unroll
    for (int ks3 = 0; ks3 < 3; ++ks3) {
      short8v bf = *reinterpret_cast<const short8v*>(qkv_wb + cw * 96 + ks3 * 32 + g * 8);
      acc = __builtin_amdgcn_mfma_f32_16x16x32_bf16(xa[ks3], bf, acc, 0, 0, 0);
    }
    const float bias = qkv_b[cw];
    if (nt < 6) {                   // q, pre-scaled by 1/sqrt(32)
      #pragma unroll
      for (int r = 0; r < 4; ++r)
        ps[w][g * 4 + r][cw] = f2bf((acc[r] + bias) * 0.17677669529663687f);
    } else if (nt < 12) {           // k row-major
      #pragma unroll
      for (int r = 0; r < 4; ++r)
        klds[w * 16 + g * 4 + r][cw - 96] = f2bf(acc[r] + bias);
    } else {                        // v transposed, 8B packed
      ushort4 pk = make_ushort4(f2bf(acc[0] + bias), f2bf(acc[1] + bias),
                                f2bf(acc[2] + bias), f2bf(acc[3] + bias));
      *reinterpret_cast<ushort4*>(&vts[cw - 192][w * 16 + g * 4]) = pk;
    }
  }
  asm volatile("" ::: "memory");

  // q D->A transpose readback (wave-private, in-order DS, no barrier needed)
  short8v qf[3];
  #pragma unroll
  for (int h = 0; h < 3; ++h)
    qf[h] = *reinterpret_cast<const short8v*>(&ps[w][l15][h * 32 + g * 8]);

  __syncthreads();   // publish klds + vts (the only barrier)

  // preload shift mask (same for all 3 heads): 16 regs
  const float* maskw = mask + (size_t)(bb & 4095) * 4096 + (w * 16) * 64 + l15;
  float mk[4][4];
  #pragma unroll
  for (int tj = 0; tj < 4; ++tj)
    #pragma unroll
    for (int r = 0; r < 4; ++r)
      mk[tj][r] = maskw[(g * 4 + r) * 64 + tj * 16];

  const float* bcb = bias_comb + (w * 16) * 64 + l15;

  f32x4 pacc[6];
  #pragma unroll
  for (int nt2 = 0; nt2 < 6; ++nt2) pacc[nt2] = (f32x4){0.f, 0.f, 0.f, 0.f};

  #pragma unroll
  for (int h = 0; h < 3; ++h) {
    // QK^T: s[tj] = q_rows x k_rows^T  (rows w*16.., cols tj*16..)
    f32x4 s[4];
    #pragma unroll
    for (int tj = 0; tj < 4; ++tj) {
      short8v kf = *reinterpret_cast<const short8v*>(&klds[tj * 16 + l15][h * 32 + g * 8]);
      f32x4 z = {0.f, 0.f, 0.f, 0.f};
      s[tj] = __builtin_amdgcn_mfma_f32_16x16x32_bf16(qf[h], kf, z, 0, 0, 0);
    }
    // + rel-pos bias + mask; row max (rows live in 16-lane groups)
    float mx[4] = {-1e30f, -1e30f, -1e30f, -1e30f};
    #pragma unroll
    for (int tj = 0; tj < 4; ++tj) {
      #pragma unroll
      for (int r = 0; r < 4; ++r) {
        float v = s[tj][r] + bcb[h * 4096 + (g * 4 + r) * 64 + tj * 16] + mk[tj][r];
        s[tj][r] = v;
        mx[r] = fmaxf(mx[r], v);
      }
    }
    #pragma unroll
    for (int r = 0; r < 4; ++r) {
      mx[r] = fmaxf(mx[r], __shfl_xor(mx[r], 1));
      mx[r] = fmaxf(mx[r], __shfl_xor(mx[r], 2));
      mx[r] = fmaxf(mx[r], __shfl_xor(mx[r], 4));
      mx[r] = fmaxf(mx[r], __shfl_xor(mx[r], 8));
    }
    float sm[4] = {0.f, 0.f, 0.f, 0.f};
    #pragma unroll
    for (int tj = 0; tj < 4; ++tj) {
      #pragma unroll
      for (int r = 0; r < 4; ++r) {
        float p = __expf(s[tj][r] - mx[r]);
        s[tj][r] = p;
        sm[r] += p;
      }
    }
    #pragma unroll
    for (int r = 0; r < 4; ++r) {
      sm[r] += __shfl_xor(sm[r], 1);
      sm[r] += __shfl_xor(sm[r], 2);
      sm[r] += __shfl_xor(sm[r], 4);
      sm[r] += __shfl_xor(sm[r], 8);
    }
    float inv[4];
    #pragma unroll
    for (int r = 0; r < 4; ++r) inv[r] = 1.0f / sm[r];

    // P (unnormalized) -> wave scratch, D->A transpose
    #pragma unroll
    for (int tj = 0; tj < 4; ++tj)
      #pragma unroll
      for (int r = 0; r < 4; ++r)
        ps[w][g * 4 + r][tj * 16 + l15] = f2bf(s[tj][r]);
    asm volatile("" ::: "memory");
    short8v ap[2];
    #pragma unroll
    for (int ks2 = 0; ks2 < 2; ++ks2)
      ap[ks2] = *reinterpret_cast<const short8v*>(&ps[w][l15][ks2 * 32 + g * 8]);

    // PV: out[16x32] = P[16x64] @ V[64x32]; fold 1/sum into epilogue
    #pragma unroll
    for (int nt = 0; nt < 2; ++nt) {
      f32x4 o = {0.f, 0.f, 0.f, 0.f};
      #pragma unroll
      for (int ks2 = 0; ks2 < 2; ++ks2) {
        short8v vf = *reinterpret_cast<const short8v*>(&vts[h * 32 + nt * 16 + l15][ks2 * 32 + g * 8]);
        o = __builtin_amdgcn_mfma_f32_16x16x32_bf16(ap[ks2], vf, o, 0, 0, 0);
      }
      #pragma unroll
      for (int r = 0; r < 4; ++r)
        ps[w][g * 4 + r][nt * 16 + l15] = f2bf(o[r] * inv[r]);
    }
    asm volatile("" ::: "memory");

    // O D->A transpose readback; accumulate output projection for this head's
    // 32-chan k-chunk: pacc[nt2] += O_h[16x32] @ projW[ch][32h..32h+31]^T
    short8v oa = *reinterpret_cast<const short8v*>(&ps[w][l15][g * 8]);
    #pragma unroll
    for (int nt2 = 0; nt2 < 6; ++nt2) {
      short8v pf = *reinterpret_cast<const short8v*>(proj_wb + (nt2 * 16 + l15) * 96 + h * 32 + g * 8);
      pacc[nt2] = __builtin_amdgcn_mfma_f32_16x16x32_bf16(oa, pf, pacc[nt2], 0, 0, 0);
    }
    asm volatile("" ::: "memory");
  }

  // epilogue: + proj bias, f32 stores (l15 consecutive -> 64B per group)
  float* ob = out + (size_t)bb * 6144 + (w * 16 + g * 4) * 96 + l15;
  #pragma unroll
  for (int nt2 = 0; nt2 < 6; ++nt2) {
    const float pb = proj_b[nt2 * 16 + l15];
    #pragma unroll
    for (int r = 0; r < 4; ++r)
      ob[r * 96 + nt2 * 16] = pacc[nt2][r] + pb;
  }
}

extern "C" void kernel_launch(void* const* d_in, const int* in_sizes, int n_in,
                              void* d_out, int out_size, void* d_ws, size_t ws_size,
                              hipStream_t stream) {
  const float* x          = (const float*)d_in[0];
  const float* mask       = (const float*)d_in[1];
  const float* qkv_w      = (const float*)d_in[2];
  const float* qkv_b      = (const float*)d_in[3];
  const float* proj_w     = (const float*)d_in[4];
  const float* proj_b     = (const float*)d_in[5];
  const float* bias_table = (const float*)d_in[6];
  const int*   rel_idx    = (const int*)d_in[7];

  char* ws = (char*)d_ws;
  ushort* qkv_wb   = (ushort*)ws;                    // 288*96*2 = 55296 B
  ushort* proj_wb  = (ushort*)(ws + 55296);          // 96*96*2  = 18432 B
  float*  bias_comb = (float*)(ws + 55296 + 18432);  // 3*64*64*4 = 49152 B

  setup_k<<<192, 256, 0, stream>>>(qkv_w, proj_w, bias_table, rel_idx,
                                   qkv_wb, proj_wb, bias_comb);
  winattn<<<8192, 256, 0, stream>>>(x, mask, qkv_b, proj_b,
                                    qkv_wb, proj_wb, bias_comb, (float*)d_out);
}

// Round 3
// 173.725 us; speedup vs baseline: 1.3648x; 1.3382x over previous
//
#include <hip/hip_runtime.h>

typedef __attribute__((ext_vector_type(8))) short short8v;
typedef __attribute__((ext_vector_type(4))) float f32x4;

__device__ __forceinline__ ushort f2bf(float f) {
  union { float f; unsigned int u; } c; c.f = f;
  return (ushort)((c.u + 0x7FFFu + ((c.u >> 16) & 1u)) >> 16);
}

// ---- setup: convert weights to bf16, pre-gather rel-pos bias to [3][64][64] f32
__global__ __launch_bounds__(256) void setup_k(
    const float* __restrict__ qkv_w, const float* __restrict__ proj_w,
    const float* __restrict__ bias_table, const int* __restrict__ rel_idx,
    ushort* __restrict__ qkv_wb, ushort* __restrict__ proj_wb,
    float* __restrict__ bias_comb) {
  int idx = blockIdx.x * 256 + threadIdx.x;
  if (idx < 27648) {                       // 288*96
    qkv_wb[idx] = f2bf(qkv_w[idx]);
  } else if (idx < 36864) {                // + 96*96
    int i = idx - 27648;
    proj_wb[i] = f2bf(proj_w[i]);
  } else if (idx < 49152) {                // + 3*64*64
    int i = idx - 36864;
    int h = i / 4096, rc = i % 4096;
    bias_comb[i] = bias_table[rel_idx[rc] * 3 + h];
  }
}

// ---- main fused kernel: one block per window PAIR {bb, bb+4096} (shared mask
// row, shared weights/bias loads, 2x independent ILP streams per wave).
// LDS = 26624 + 27648 + 25600 = 79872 B -> 2 blocks/CU.
__global__ __launch_bounds__(256, 2) void winattn(
    const float* __restrict__ x, const float* __restrict__ mask,
    const float* __restrict__ qkv_b, const float* __restrict__ proj_b,
    const ushort* __restrict__ qkv_wb, const ushort* __restrict__ proj_wb,
    const float* __restrict__ bias_comb, float* __restrict__ out) {
  // row strides (shorts): 104 (13x16B), 72 (9x16B), 200 (25x16B) — all odd
  // multiples of 16B -> conflict-free b128 column reads.
  __shared__ ushort klds[2][64][104];  // k row-major per window
  __shared__ ushort vts[2][96][72];    // v transposed per window
  __shared__ ushort ps[4][16][200];    // wave-private scratch: q x2 / P x2 / O x2

  const int bb = blockIdx.x;           // 0..4095
  const int t = threadIdx.x;
  const int w = t >> 6;
  const int lane = t & 63;
  const int l15 = lane & 15;
  const int g = lane >> 4;

  // phase A: x A-fragments for both windows straight from global
  short8v xa[2][3];
  #pragma unroll
  for (int u = 0; u < 2; ++u) {
    const float* xrow = x + ((size_t)(bb + u * 4096) * 64 + w * 16 + l15) * 96 + g * 8;
    #pragma unroll
    for (int ks3 = 0; ks3 < 3; ++ks3) {
      float4 a0 = *reinterpret_cast<const float4*>(xrow + ks3 * 32);
      float4 a1 = *reinterpret_cast<const float4*>(xrow + ks3 * 32 + 4);
      short8v v;
      v[0] = (short)f2bf(a0.x); v[1] = (short)f2bf(a0.y);
      v[2] = (short)f2bf(a0.z); v[3] = (short)f2bf(a0.w);
      v[4] = (short)f2bf(a1.x); v[5] = (short)f2bf(a1.y);
      v[6] = (short)f2bf(a1.z); v[7] = (short)f2bf(a1.w);
      xa[u][ks3] = v;
    }
  }

  // phase B: QKV GEMM; B-fragments loaded ONCE, used by both windows
  #pragma unroll
  for (int nt = 0; nt < 18; ++nt) {
    const int cw = nt * 16 + l15;
    short8v bf[3];
    #pragma unroll
    for (int ks3 = 0; ks3 < 3; ++ks3)
      bf[ks3] = *reinterpret_cast<const short8v*>(qkv_wb + cw * 96 + ks3 * 32 + g * 8);
    const float bias = qkv_b[cw];
    #pragma unroll
    for (int u = 0; u < 2; ++u) {
      f32x4 acc = {0.f, 0.f, 0.f, 0.f};
      #pragma unroll
      for (int ks3 = 0; ks3 < 3; ++ks3)
        acc = __builtin_amdgcn_mfma_f32_16x16x32_bf16(xa[u][ks3], bf[ks3], acc, 0, 0, 0);
      if (nt < 6) {                   // q (pre-scaled) -> wave scratch
        #pragma unroll
        for (int r = 0; r < 4; ++r)
          ps[w][g * 4 + r][u * 96 + cw] = f2bf((acc[r] + bias) * 0.17677669529663687f);
      } else if (nt < 12) {           // k row-major
        #pragma unroll
        for (int r = 0; r < 4; ++r)
          klds[u][w * 16 + g * 4 + r][cw - 96] = f2bf(acc[r] + bias);
      } else {                        // v transposed, 8B packed
        ushort4 pk = make_ushort4(f2bf(acc[0] + bias), f2bf(acc[1] + bias),
                                  f2bf(acc[2] + bias), f2bf(acc[3] + bias));
        *reinterpret_cast<ushort4*>(&vts[u][cw - 192][w * 16 + g * 4]) = pk;
      }
    }
  }
  asm volatile("" ::: "memory");

  // q D->A transpose readback (wave-private; no barrier needed)
  short8v qf[2][3];
  #pragma unroll
  for (int u = 0; u < 2; ++u)
    #pragma unroll
    for (int h = 0; h < 3; ++h)
      qf[u][h] = *reinterpret_cast<const short8v*>(&ps[w][l15][u * 96 + h * 32 + g * 8]);

  // preload mask (shared by both windows) + rel-pos bias for ALL heads;
  // issued before the barrier so L2 latency overlaps the barrier wait.
  const float* maskw = mask + (size_t)bb * 4096 + (w * 16) * 64 + l15;
  float mk[4][4];
  #pragma unroll
  for (int tj = 0; tj < 4; ++tj)
    #pragma unroll
    for (int r = 0; r < 4; ++r)
      mk[tj][r] = maskw[(g * 4 + r) * 64 + tj * 16];
  const float* bcb = bias_comb + (w * 16) * 64 + l15;
  float bc[3][4][4];
  #pragma unroll
  for (int h = 0; h < 3; ++h)
    #pragma unroll
    for (int tj = 0; tj < 4; ++tj)
      #pragma unroll
      for (int r = 0; r < 4; ++r)
        bc[h][tj][r] = bcb[h * 4096 + (g * 4 + r) * 64 + tj * 16];

  __syncthreads();   // publish klds + vts (the only barrier)

  f32x4 pacc[2][6];
  #pragma unroll
  for (int u = 0; u < 2; ++u)
    #pragma unroll
    for (int nt2 = 0; nt2 < 6; ++nt2) pacc[u][nt2] = (f32x4){0.f, 0.f, 0.f, 0.f};

  #pragma unroll
  for (int h = 0; h < 3; ++h) {
    // QK^T for both windows (independent MFMA streams)
    f32x4 s[2][4];
    #pragma unroll
    for (int tj = 0; tj < 4; ++tj) {
      #pragma unroll
      for (int u = 0; u < 2; ++u) {
        short8v kf = *reinterpret_cast<const short8v*>(&klds[u][tj * 16 + l15][h * 32 + g * 8]);
        f32x4 z = {0.f, 0.f, 0.f, 0.f};
        s[u][tj] = __builtin_amdgcn_mfma_f32_16x16x32_bf16(qf[u][h], kf, z, 0, 0, 0);
      }
    }
    // bias + mask + row max
    float mx[2][4];
    #pragma unroll
    for (int u = 0; u < 2; ++u)
      #pragma unroll
      for (int r = 0; r < 4; ++r) mx[u][r] = -1e30f;
    #pragma unroll
    for (int tj = 0; tj < 4; ++tj) {
      #pragma unroll
      for (int r = 0; r < 4; ++r) {
        const float bm = bc[h][tj][r] + mk[tj][r];
        #pragma unroll
        for (int u = 0; u < 2; ++u) {
          float v = s[u][tj][r] + bm;
          s[u][tj][r] = v;
          mx[u][r] = fmaxf(mx[u][r], v);
        }
      }
    }
    #pragma unroll
    for (int st = 1; st <= 8; st <<= 1)
      #pragma unroll
      for (int u = 0; u < 2; ++u)
        #pragma unroll
        for (int r = 0; r < 4; ++r)
          mx[u][r] = fmaxf(mx[u][r], __shfl_xor(mx[u][r], st));
    float sm[2][4];
    #pragma unroll
    for (int u = 0; u < 2; ++u)
      #pragma unroll
      for (int r = 0; r < 4; ++r) sm[u][r] = 0.f;
    #pragma unroll
    for (int tj = 0; tj < 4; ++tj)
      #pragma unroll
      for (int r = 0; r < 4; ++r)
        #pragma unroll
        for (int u = 0; u < 2; ++u) {
          float p = __expf(s[u][tj][r] - mx[u][r]);
          s[u][tj][r] = p;
          sm[u][r] += p;
        }
    #pragma unroll
    for (int st = 1; st <= 8; st <<= 1)
      #pragma unroll
      for (int u = 0; u < 2; ++u)
        #pragma unroll
        for (int r = 0; r < 4; ++r)
          sm[u][r] += __shfl_xor(sm[u][r], st);
    float inv[2][4];
    #pragma unroll
    for (int u = 0; u < 2; ++u)
      #pragma unroll
      for (int r = 0; r < 4; ++r) inv[u][r] = 1.0f / sm[u][r];

    // P (unnormalized) -> wave scratch (win0 cols 0..63, win1 cols 64..127)
    #pragma unroll
    for (int u = 0; u < 2; ++u)
      #pragma unroll
      for (int tj = 0; tj < 4; ++tj)
        #pragma unroll
        for (int r = 0; r < 4; ++r)
          ps[w][g * 4 + r][u * 64 + tj * 16 + l15] = f2bf(s[u][tj][r]);
    asm volatile("" ::: "memory");
    short8v ap[2][2];
    #pragma unroll
    for (int u = 0; u < 2; ++u)
      #pragma unroll
      for (int ks2 = 0; ks2 < 2; ++ks2)
        ap[u][ks2] = *reinterpret_cast<const short8v*>(&ps[w][l15][u * 64 + ks2 * 32 + g * 8]);

    // PV for both windows; fold 1/sum into O store
    #pragma unroll
    for (int nt = 0; nt < 2; ++nt) {
      #pragma unroll
      for (int u = 0; u < 2; ++u) {
        f32x4 o = {0.f, 0.f, 0.f, 0.f};
        #pragma unroll
        for (int ks2 = 0; ks2 < 2; ++ks2) {
          short8v vf = *reinterpret_cast<const short8v*>(&vts[u][h * 32 + nt * 16 + l15][ks2 * 32 + g * 8]);
          o = __builtin_amdgcn_mfma_f32_16x16x32_bf16(ap[u][ks2], vf, o, 0, 0, 0);
        }
        #pragma unroll
        for (int r = 0; r < 4; ++r)
          ps[w][g * 4 + r][u * 32 + nt * 16 + l15] = f2bf(o[r] * inv[u][r]);
      }
    }
    asm volatile("" ::: "memory");

    // O readback; per-head output-proj accumulate (proj B-frags loaded once)
    short8v oa[2];
    #pragma unroll
    for (int u = 0; u < 2; ++u)
      oa[u] = *reinterpret_cast<const short8v*>(&ps[w][l15][u * 32 + g * 8]);
    #pragma unroll
    for (int nt2 = 0; nt2 < 6; ++nt2) {
      short8v pf = *reinterpret_cast<const short8v*>(proj_wb + (nt2 * 16 + l15) * 96 + h * 32 + g * 8);
      #pragma unroll
      for (int u = 0; u < 2; ++u)
        pacc[u][nt2] = __builtin_amdgcn_mfma_f32_16x16x32_bf16(oa[u], pf, pacc[u][nt2], 0, 0, 0);
    }
    asm volatile("" ::: "memory");
  }

  // epilogue: + proj bias, f32 stores for both windows
  float pb[6];
  #pragma unroll
  for (int nt2 = 0; nt2 < 6; ++nt2) pb[nt2] = proj_b[nt2 * 16 + l15];
  #pragma unroll
  for (int u = 0; u < 2; ++u) {
    float* ob = out + (size_t)(bb + u * 4096) * 6144 + (w * 16 + g * 4) * 96 + l15;
    #pragma unroll
    for (int nt2 = 0; nt2 < 6; ++nt2)
      #pragma unroll
      for (int r = 0; r < 4; ++r)
        ob[r * 96 + nt2 * 16] = pacc[u][nt2][r] + pb[nt2];
  }
}

extern "C" void kernel_launch(void* const* d_in, const int* in_sizes, int n_in,
                              void* d_out, int out_size, void* d_ws, size_t ws_size,
                              hipStream_t stream) {
  const float* x          = (const float*)d_in[0];
  const float* mask       = (const float*)d_in[1];
  const float* qkv_w      = (const float*)d_in[2];
  const float* qkv_b      = (const float*)d_in[3];
  const float* proj_w     = (const float*)d_in[4];
  const float* proj_b     = (const float*)d_in[5];
  const float* bias_table = (const float*)d_in[6];
  const int*   rel_idx    = (const int*)d_in[7];

  char* ws = (char*)d_ws;
  ushort* qkv_wb   = (ushort*)ws;                    // 288*96*2 = 55296 B
  ushort* proj_wb  = (ushort*)(ws + 55296);          // 96*96*2  = 18432 B
  float*  bias_comb = (float*)(ws + 55296 + 18432);  // 3*64*64*4 = 49152 B

  setup_k<<<192, 256, 0, stream>>>(qkv_w, proj_w, bias_table, rel_idx,
                                   qkv_wb, proj_wb, bias_comb);
  winattn<<<4096, 256, 0, stream>>>(x, mask, qkv_b, proj_b,
                                    qkv_wb, proj_wb, bias_comb, (float*)d_out);
}